// Round 11
// baseline (179.028 us; speedup 1.0000x reference)
//
#include <hip/hip_runtime.h>

namespace {

constexpr int kB  = 16384;  // rods
constexpr int kNV = 129;    // vertices per rod
constexpr int kNE = 128;    // edges per rod
constexpr int kWPB = 4;     // waves per block
constexpr int kRPW = 4;     // rods per wave (one per 16-lane DPP row)

typedef float v2f __attribute__((ext_vector_type(2)));
typedef float v4f __attribute__((ext_vector_type(4)));

struct F3 { float x, y, z; };
struct Q4 { float w, x, y, z; };   // fp32 quaternion

// ---- DPP row_shr:N — shifts within 16-lane rows == rod groups (VALU, no DS) ----
template<int N>
__device__ __forceinline__ int rsr_i(int x) {
    return __builtin_amdgcn_update_dpp(x, x, 0x110 + N, 0xf, 0xf, false);
}
template<int N>
__device__ __forceinline__ float rsr_f(float x) {
    return __int_as_float(rsr_i<N>(__float_as_int(x)));
}
template<int N>
__device__ __forceinline__ double rsr_d(double x) {
    const long long v = __double_as_longlong(x);
    const int lo = (int)(unsigned int)(v & 0xffffffffull);
    const int hi = (int)(v >> 32);
    const int rlo = rsr_i<N>(lo);
    const int rhi = rsr_i<N>(hi);
    return __longlong_as_double(((long long)(unsigned int)rlo) | (((long long)rhi) << 32));
}

__device__ __forceinline__ F3 crossf(F3 a, F3 b) {
    return { a.y*b.z - a.z*b.y,
             a.z*b.x - a.x*b.z,
             a.x*b.y - a.y*b.x };
}
__device__ __forceinline__ float dotf(F3 a, F3 b) { return a.x*b.x + a.y*b.y + a.z*b.z; }
__device__ __forceinline__ F3 subf(F3 a, F3 b) { return { a.x-b.x, a.y-b.y, a.z-b.z }; }
// matches ref _normalize: x / max(|x|, 1e-12)
__device__ __forceinline__ F3 nrmf(F3 a) {
    const float s = 1.0f / fmaxf(sqrtf(dotf(a, a)), 1e-12f);
    return { a.x*s, a.y*s, a.z*s };
}
// a (x) b : apply b first, then a
__device__ __forceinline__ Q4 qmul(Q4 a, Q4 b) {
    return { a.w*b.w - a.x*b.x - a.y*b.y - a.z*b.z,
             a.w*b.x + a.x*b.w + a.y*b.z - a.z*b.y,
             a.w*b.y - a.x*b.z + a.y*b.w + a.z*b.x,
             a.w*b.z + a.x*b.y - a.y*b.x + a.z*b.w };
}
template<int N>
__device__ __forceinline__ Q4 rsr_q(Q4 a) {
    return { rsr_f<N>(a.w), rsr_f<N>(a.x), rsr_f<N>(a.y), rsr_f<N>(a.z) };
}
// rotate x by unit quaternion q: x + 2w(v x x) + 2 v x (v x x)
__device__ __forceinline__ F3 qrot(Q4 q, F3 x) {
    const F3 v  = { q.x, q.y, q.z };
    const F3 t  = crossf(v, x);
    const F3 t2 = crossf(v, t);
    return { x.x + 2.0f*(q.w*t.x + t2.x),
             x.y + 2.0f*(q.w*t.y + t2.y),
             x.z + 2.0f*(q.w*t.z + t2.z) };
}
__device__ __forceinline__ void nts2(float* p, float a, float b) {
    v2f v = { a, b };
    __builtin_nontemporal_store(v, (v2f*)p);
}
__device__ __forceinline__ void nts4(float* p, float a, float b, float c, float d) {
    v4f v = { a, b, c, d };
    __builtin_nontemporal_store(v, (v4f*)p);
}

__global__ __launch_bounds__(256, 4)
void rod_frames_scan_kernel(const float* __restrict__ verts,   // (B, 129, 3)
                            const float* __restrict__ dinit,   // (B, 3)
                            const float* __restrict__ restL,   // (B, 128)
                            float* __restrict__ out)           // [b_u | b_v | kb]
{
    const int lane = threadIdx.x & 63;
    const int lig  = lane & 15;                                  // lane in 16-lane group
    const int wid  = blockIdx.x * kWPB + (threadIdx.x >> 6);
    const int b    = wid * kRPW + (lane >> 4);                   // rod id

    const float* V  = verts + (size_t)b * (kNV*3);
    const float* vb = V + 24*lig;

    // ---- own 27 vertex floats = vertices 8*lig .. 8*lig+8 (contiguous 96B/lane) ----
    float w[27];
    #pragma unroll
    for (int t = 0; t < 13; ++t) {
        const float2 tt = *(const float2*)(vb + 2*t);
        w[2*t] = tt.x; w[2*t+1] = tt.y;
    }
    w[26] = vb[26];

    // ---- rest lengths L[8*lig .. 8*lig+7] (16B aligned) ----
    float Lv[8];
    {
        const float* lb = restL + (size_t)b * kNE + 8*lig;
        const float4 t0 = *(const float4*)(lb);
        const float4 t1 = *(const float4*)(lb + 4);
        Lv[0]=t0.x; Lv[1]=t0.y; Lv[2]=t0.z; Lv[3]=t0.w;
        Lv[4]=t1.x; Lv[5]=t1.y; Lv[6]=t1.z; Lv[7]=t1.w;
    }

    // ---- neighbor handoff: previous lane's LAST edge (fp64, exact) + last L ----
    const double e7x = (double)w[24] - (double)w[21];
    const double e7y = (double)w[25] - (double)w[22];
    const double e7z = (double)w[26] - (double)w[23];
    double ePx = rsr_d<1>(e7x);    // lig==0: garbage, unused (anchor)
    double ePy = rsr_d<1>(e7y);
    double ePz = rsr_d<1>(e7z);
    const float lPf = rsr_f<1>(Lv[7]);

    float* bu  = out + (size_t)b * (kNE*3) + 24*lig;
    float* bv  = bu  + (size_t)kB * (kNE*3);
    float* kbo = bv  + (size_t)kB * (kNE*3);

    // ---- loop 1: edges (fp64), kb (fp64 denom), q_k, local prefix chain ----
    F3 Ef[8];
    Q4 Pl[8];
    Q4 qloc = {1.f, 0.f, 0.f, 0.f};
    unsigned am = 0;            // active mask, bit k = edge 8*lig+k
    F3 kbprev = {0.f,0.f,0.f};

    #pragma unroll
    for (int k = 0; k < 8; ++k) {
        const double edx = (double)w[3*k+3] - (double)w[3*k+0];
        const double edy = (double)w[3*k+4] - (double)w[3*k+1];
        const double edz = (double)w[3*k+5] - (double)w[3*k+2];
        const F3 ef = { (float)edx, (float)edy, (float)edz };
        Ef[k] = ef;

        F3 kb = {0.f, 0.f, 0.f};
        Q4 q  = {1.f, 0.f, 0.f, 0.f};
        bool act = (lig == 0 && k == 0);        // rod edge 0: anchor
        if (!act) {
            const double lp = (k == 0) ? (double)lPf : (double)Lv[k-1];
            const double denom = lp*(double)Lv[k] + (ePx*edx + ePy*edy + ePz*edz);
            const F3 ePf = { (float)ePx, (float)ePy, (float)ePz };
            const F3 c = crossf(ePf, ef);
            const float rd = 2.0f / (float)denom;
            kb = { c.x*rd, c.y*rd, c.z*rd };
            const float mag = dotf(kb, kb);
            const float inv = 1.0f / (4.0f + mag);
            const float ww  = sqrtf(4.0f * inv);
            if (1.0f - ww > 1e-6f) {
                act = true;
                const float sp = sqrtf(mag * inv);                 // sinPhi
                const float as = sp / fmaxf(sqrtf(mag), 1e-12f);   // sinPhi/|kb|
                q = { ww, kb.x*as, kb.y*as, kb.z*as };
            }
        }
        if (act) am |= (1u << k);
        qloc = (k == 0) ? q : qmul(q, qloc);
        Pl[k] = qloc;

        if (k & 1) {   // store kb pair (edges k-1, k): 6 floats, alignment by k
            const int off = 3*(k-1);
            if (((k-1) & 2) == 0) { nts4(kbo+off, kbprev.x, kbprev.y, kbprev.z, kb.x); nts2(kbo+off+4, kb.y, kb.z); }
            else                  { nts2(kbo+off, kbprev.x, kbprev.y); nts4(kbo+off+2, kbprev.z, kb.x, kb.y, kb.z); }
        } else {
            kbprev = kb;
        }

        ePx = edx; ePy = edy; ePz = edz;
    }

    // ---- 16-lane Kogge-Stone scan of quaternion products, all via DPP row_shr ----
    Q4 s = qloc;
    { const Q4 t = rsr_q<1>(s); if (lig >= 1) s = qmul(s, t); }
    { const Q4 t = rsr_q<2>(s); if (lig >= 2) s = qmul(s, t); }
    { const Q4 t = rsr_q<4>(s); if (lig >= 4) s = qmul(s, t); }
    { const Q4 t = rsr_q<8>(s); if (lig >= 8) s = qmul(s, t); }
    Q4 ex = rsr_q<1>(s);
    if (lig == 0) ex = {1.f, 0.f, 0.f, 0.f};

    // ---- last-active-index max-scan (DPP) ----
    const int hk = am ? (8*lig + (31 - __builtin_clz(am))) : -1;
    int m = hk;
    { const int t = rsr_i<1>(m); if (lig >= 1) m = max(m, t); }
    { const int t = rsr_i<2>(m); if (lig >= 2) m = max(m, t); }
    { const int t = rsr_i<4>(m); if (lig >= 4) m = max(m, t); }
    { const int t = rsr_i<8>(m); if (lig >= 8) m = max(m, t); }
    int exm = rsr_i<1>(m);
    if (lig == 0) exm = -1;

    // ---- u0 per rod (uniform within group; L1-served loads) ----
    const F3 dvf = { dinit[3*b+0], dinit[3*b+1], dinit[3*b+2] };
    const F3 p0  = { V[0], V[1], V[2] };
    const F3 p1  = { V[3], V[4], V[5] };
    const F3 e0f = subf(p1, p0);
    const F3 u0  = nrmf(crossf(crossf(e0f, dvf), e0f));
    const F3 u0p = qrot(ex, u0);    // R(Pl_k (x) ex) u0 == R(Pl_k) (R(ex) u0)

    // ---- v-carry: j = last active edge <= i; cold reload if j != i (rare) ----
    int jv[8];
    bool anyj = false;
    #pragma unroll
    for (int k = 0; k < 8; ++k) {
        const int i = 8*lig + k;
        const unsigned lm = am & ((2u << k) - 1u);
        const int j = lm ? (8*lig + (31 - __builtin_clz(lm))) : exm;
        jv[k] = j;
        anyj |= (j != i);
    }
    if (__any(anyj)) {
        #pragma unroll
        for (int k = 0; k < 8; ++k) {
            if (jv[k] != 8*lig + k) {
                const float* pj = V + 3*jv[k];
                const double dx = (double)pj[3] - (double)pj[0];
                const double dy = (double)pj[4] - (double)pj[1];
                const double dz = (double)pj[5] - (double)pj[2];
                Ef[k] = { (float)dx, (float)dy, (float)dz };
            }
        }
    }

    // ---- loop 2: u_k, v_k, paired NT stores ----
    F3 up = {0,0,0}, vp = {0,0,0};
    #pragma unroll
    for (int k = 0; k < 8; ++k) {
        const F3 u = qrot(Pl[k], u0p);
        const F3 v = nrmf(crossf(Ef[k], u));
        if (k & 1) {
            const int off = 3*(k-1);
            if (((k-1) & 2) == 0) {
                nts4(bu+off, up.x, up.y, up.z, u.x); nts2(bu+off+4, u.y, u.z);
                nts4(bv+off, vp.x, vp.y, vp.z, v.x); nts2(bv+off+4, v.y, v.z);
            } else {
                nts2(bu+off, up.x, up.y); nts4(bu+off+2, up.z, u.x, u.y, u.z);
                nts2(bv+off, vp.x, vp.y); nts4(bv+off+2, vp.z, v.x, v.y, v.z);
            }
        } else {
            up = u; vp = v;
        }
    }
}

} // namespace

extern "C" void kernel_launch(void* const* d_in, const int* in_sizes, int n_in,
                              void* d_out, int out_size, void* d_ws, size_t ws_size,
                              hipStream_t stream)
{
    const float* verts = (const float*)d_in[0];
    const float* dinit = (const float*)d_in[1];
    const float* restL = (const float*)d_in[2];
    float* out = (float*)d_out;

    dim3 grid(kB / (kWPB * kRPW));   // 1024 blocks x 4 waves x 4 rods = 16384 rods
    dim3 block(64 * kWPB);
    hipLaunchKernelGGL(rod_frames_scan_kernel, grid, block, 0, stream,
                       verts, dinit, restL, out);
}

// Round 13
// 26.957 us; speedup vs baseline: 6.6413x; 6.6413x over previous
//
#include <hip/hip_runtime.h>

namespace {

constexpr int kB  = 16384;  // rods
constexpr int kNV = 129;    // vertices per rod
constexpr int kNE = 128;    // edges per rod
constexpr int kRPB = 4;     // rods (= waves) per block

typedef float v2f __attribute__((ext_vector_type(2)));   // NT-store-compatible

struct F3 { float x, y, z; };
struct Q4 { float w, x, y, z; };   // fp32 quaternion

// ---- DPP cross-lane (all VALU, no DS); ctrl must be a compile-time constant ----
// wave_shr:1 (0x138): lane i <- i-1 whole-wave; wave_shl:1 (0x130): lane i <- i+1
// row_shr:N (0x110+N): lane i <- i-N within 16-lane row (lig<N keep old)
// row_bcast15 (0x142): each row's lane15 -> next row; row_bcast31 (0x143): lane31 -> rows 2,3
template<int CTRL>
__device__ __forceinline__ int dpp_i(int x) {
    return __builtin_amdgcn_update_dpp(x, x, CTRL, 0xf, 0xf, false);
}
template<int CTRL>
__device__ __forceinline__ float dpp_f(float x) {
    return __int_as_float(dpp_i<CTRL>(__float_as_int(x)));
}
__device__ __forceinline__ float dpp_up1(float x) { return dpp_f<0x138>(x); }
__device__ __forceinline__ float dpp_dn1(float x) { return dpp_f<0x130>(x); }
__device__ __forceinline__ double dpp_up1_d(double x) {
    const long long v = __double_as_longlong(x);
    const int rlo = dpp_i<0x138>((int)(v & 0xffffffffll));
    const int rhi = dpp_i<0x138>((int)(v >> 32));
    return __longlong_as_double(((long long)(unsigned int)rlo) | (((long long)rhi) << 32));
}

__device__ __forceinline__ F3 crossf(F3 a, F3 b) {
    return { a.y*b.z - a.z*b.y,
             a.z*b.x - a.x*b.z,
             a.x*b.y - a.y*b.x };
}
__device__ __forceinline__ float dotf(F3 a, F3 b) { return a.x*b.x + a.y*b.y + a.z*b.z; }
__device__ __forceinline__ F3 subf(F3 a, F3 b) { return { a.x-b.x, a.y-b.y, a.z-b.z }; }
// matches ref _normalize: x / max(|x|, 1e-12)
__device__ __forceinline__ F3 nrmf(F3 a) {
    const float s = 1.0f / fmaxf(sqrtf(dotf(a, a)), 1e-12f);
    return { a.x*s, a.y*s, a.z*s };
}
// a (x) b : apply b first, then a
__device__ __forceinline__ Q4 qmul(Q4 a, Q4 b) {
    return { a.w*b.w - a.x*b.x - a.y*b.y - a.z*b.z,
             a.w*b.x + a.x*b.w + a.y*b.z - a.z*b.y,
             a.w*b.y - a.x*b.z + a.y*b.w + a.z*b.x,
             a.w*b.z + a.x*b.y - a.y*b.x + a.z*b.w };
}
// rotate x by unit quaternion q: x + 2w(v x x) + 2 v x (v x x)
__device__ __forceinline__ F3 qrot(Q4 q, F3 x) {
    const F3 v  = { q.x, q.y, q.z };
    const F3 t  = crossf(v, x);
    const F3 t2 = crossf(v, t);
    return { x.x + 2.0f*(q.w*t.x + t2.x),
             x.y + 2.0f*(q.w*t.y + t2.y),
             x.z + 2.0f*(q.w*t.z + t2.z) };
}
template<int CTRL>
__device__ __forceinline__ Q4 dpp_q(Q4 a) {
    return { dpp_f<CTRL>(a.w), dpp_f<CTRL>(a.x), dpp_f<CTRL>(a.y), dpp_f<CTRL>(a.z) };
}
// highest set bit index, m != 0
__device__ __forceinline__ int hbit(unsigned long long m) {
    return 63 - __builtin_clzll(m);
}
__device__ __forceinline__ void nts2(float* p, float a, float bq) {
    v2f v = { a, bq };
    __builtin_nontemporal_store(v, (v2f*)p);
}

__global__ __launch_bounds__(256)
void rod_frames_scan_kernel(const float* __restrict__ verts,   // (B, 129, 3)
                            const float* __restrict__ dinit,   // (B, 3)
                            const float* __restrict__ restL,   // (B, 128)
                            float* __restrict__ out)           // [b_u | b_v | kb]
{
    const int wave = threadIdx.x >> 6;
    const int lane = threadIdx.x & 63;
    const int lig  = lane & 15;
    const int b = blockIdx.x * kRPB + wave;

    const int i0 = 2*lane, i1 = 2*lane + 1;

    // ---- per-lane vertex loads: ONLY own 2 vertices (3x float2, 8B aligned) ----
    const float2* V2 = (const float2*)(verts + (size_t)b * (kNV*3));
    const float2 f0 = V2[3*lane + 0];
    const float2 f1 = V2[3*lane + 1];
    const float2 f2 = V2[3*lane + 2];
    const F3 vA = { f0.x, f0.y, f1.x };   // vertex 2l
    const F3 vB = { f1.y, f2.x, f2.y };   // vertex 2l+1

    // ---- wave-uniform reads -> scalar pipe ----
    const int bw = __builtin_amdgcn_readfirstlane(b);
    const float* Vu = verts + (size_t)bw * (kNV*3);
    const F3 vLast = { Vu[kNE*3+0], Vu[kNE*3+1], Vu[kNE*3+2] };   // vertex 128
    const F3 dvf   = { dinit[bw*3+0], dinit[bw*3+1], dinit[bw*3+2] };
    const F3 p0    = { Vu[0], Vu[1], Vu[2] };
    const F3 p1    = { Vu[3], Vu[4], Vu[5] };

    // ---- vC (vertex 2l+2) from neighbor lane via DPP; lane 63 takes vertex 128 ----
    F3 vC = { dpp_dn1(vA.x), dpp_dn1(vA.y), dpp_dn1(vA.z) };
    if (lane == 63) vC = vLast;

    // ---- fp64 edges (exact: fp32 promotes exactly, diffs fit 53 bits) ----
    const double eAdx = (double)vB.x - (double)vA.x;   // e_{2l}
    const double eAdy = (double)vB.y - (double)vA.y;
    const double eAdz = (double)vB.z - (double)vA.z;
    const double eBdx = (double)vC.x - (double)vB.x;   // e_{2l+1}
    const double eBdy = (double)vC.y - (double)vB.y;
    const double eBdz = (double)vC.z - (double)vB.z;
    // e_{2l-1} = previous lane's eB via DPP (bit-identical; lane 0 unused)
    const double ePdx = dpp_up1_d(eBdx);
    const double ePdy = dpp_up1_d(eBdy);
    const double ePdz = dpp_up1_d(eBdz);

    const F3 eAf = { (float)eAdx, (float)eAdy, (float)eAdz };
    const F3 eBf = { (float)eBdx, (float)eBdy, (float)eBdz };
    const F3 ePf = { (float)ePdx, (float)ePdy, (float)ePdz };

    // ---- u0 (identical in every lane), fp32 ----
    const F3 e0f = subf(p1, p0);
    const F3 u0  = nrmf(crossf(crossf(e0f, dvf), e0f));

    // ---- rest lengths: own pair + neighbor's high half via DPP ----
    const float2 Lp = *(const float2*)(restL + (size_t)b*kNE + i0);
    const float lPf = dpp_up1(Lp.y);   // L[i0-1] (lane 0: unused)
    const double lA = (double)Lp.x;
    const double lB = (double)Lp.y;
    const double lP = (double)lPf;

    // ---- per-slot kb (fp64 denom, fp32 numerator), quaternion, activity ----
    F3  kb0 = {0.f, 0.f, 0.f};
    Q4  q0  = {1.f, 0.f, 0.f, 0.f};
    bool act0 = (lane == 0);          // index 0 is the u0/v0 anchor
    if (lane > 0) {
        const double denom = lP*lA + (ePdx*eAdx + ePdy*eAdy + ePdz*eAdz);
        const F3 c = crossf(ePf, eAf);
        const float rd = 2.0f / (float)denom;
        kb0 = { c.x*rd, c.y*rd, c.z*rd };
        const float mag = dotf(kb0, kb0);
        const float inv = 1.0f / (4.0f + mag);
        const float w   = sqrtf(4.0f * inv);
        if (1.0f - w > 1e-6f) {
            act0 = true;
            const float sp = sqrtf(mag * inv);                    // sinPhi
            const float as = sp / fmaxf(sqrtf(mag), 1e-12f);      // sinPhi/|kb|
            q0 = { w, kb0.x*as, kb0.y*as, kb0.z*as };
        }
    }

    F3  kb1;
    Q4  q1  = {1.f, 0.f, 0.f, 0.f};
    bool act1 = false;
    {
        const double denom = lA*lB + (eAdx*eBdx + eAdy*eBdy + eAdz*eBdz);
        const F3 c = crossf(eAf, eBf);
        const float rd = 2.0f / (float)denom;
        kb1 = { c.x*rd, c.y*rd, c.z*rd };
        const float mag = dotf(kb1, kb1);
        const float inv = 1.0f / (4.0f + mag);
        const float w   = sqrtf(4.0f * inv);
        if (1.0f - w > 1e-6f) {
            act1 = true;
            const float sp = sqrtf(mag * inv);
            const float as = sp / fmaxf(sqrtf(mag), 1e-12f);
            q1 = { w, kb1.x*as, kb1.y*as, kb1.z*as };
        }
    }

    // ---- whole-wave inclusive scan of quaternion products, 100% DPP (no DS):
    //      row-local Kogge-Stone (row_shr 1,2,4,8) + row_bcast15 + row_bcast31 ----
    Q4 s = qmul(q1, q0);
    { const Q4 t = dpp_q<0x111>(s); if (lig >= 1) s = qmul(s, t); }
    { const Q4 t = dpp_q<0x112>(s); if (lig >= 2) s = qmul(s, t); }
    { const Q4 t = dpp_q<0x114>(s); if (lig >= 4) s = qmul(s, t); }
    { const Q4 t = dpp_q<0x118>(s); if (lig >= 8) s = qmul(s, t); }
    { const Q4 t = dpp_q<0x142>(s);                    // row_bcast15 -> rows 1,3
      const int row = lane >> 4;
      if (row == 1 || row == 3) s = qmul(s, t); }
    { const Q4 t = dpp_q<0x143>(s);                    // row_bcast31 -> rows 2,3
      if (lane >= 32) s = qmul(s, t); }
    Q4 ex = dpp_q<0x138>(s);                           // wave_shr:1 (exclusive shift)
    if (lane == 0) ex = {1.f, 0.f, 0.f, 0.f};
    const Q4 Qa = qmul(q0, ex);   // composed rotation up to index i0
    const Q4 Qb = s;              // composed rotation up to index i1

    // ---- last-active-index via ballot + clz ----
    const unsigned long long mask0 = __ballot(act0);   // bit l = act at slot 2l
    const unsigned long long mask1 = __ballot(act1);   // bit l = act at slot 2l+1
    const unsigned long long m0a = mask0 & (~0ull >> (63 - lane));          // bits 0..l (nonempty: bit0 set)
    const unsigned long long m1a = lane ? (mask1 & (~0ull >> (64 - lane))) : 0ull; // bits 0..l-1
    const int j0 = max(2*hbit(m0a), m1a ? 2*hbit(m1a)+1 : -1);
    const unsigned long long m1b = mask1 & (~0ull >> (63 - lane));          // bits 0..l
    const int j1 = max(2*hbit(m0a), m1b ? 2*hbit(m1b)+1 : -1);

    // ---- u_i = R(Q_i) u0 ----
    const F3 uA = qrot(Qa, u0);
    const F3 uB = qrot(Qb, u0);

    // ---- edges at j0/j1: almost always own eA/eB; rare wave-uniform gather ----
    F3 ej0 = eAf, ej1 = eBf;
    if (__any((j0 != i0) || (j1 != i1))) {
        const int s0 = j0 >> 1, s1 = j1 >> 1;
        const F3 a0 = { __shfl(eAf.x, s0, 64), __shfl(eAf.y, s0, 64), __shfl(eAf.z, s0, 64) };
        const F3 b0 = { __shfl(eBf.x, s0, 64), __shfl(eBf.y, s0, 64), __shfl(eBf.z, s0, 64) };
        const F3 a1 = { __shfl(eAf.x, s1, 64), __shfl(eAf.y, s1, 64), __shfl(eAf.z, s1, 64) };
        const F3 b1 = { __shfl(eBf.x, s1, 64), __shfl(eBf.y, s1, 64), __shfl(eBf.z, s1, 64) };
        ej0 = (j0 & 1) ? b0 : a0;
        ej1 = (j1 & 1) ? b1 : a1;
    }

    const F3 vvA = nrmf(crossf(ej0, uA));
    const F3 vvB = nrmf(crossf(ej1, uB));

    // ---- coalesced NT stores (empirically -2.3us vs plain despite +10MB WRITE_SIZE) ----
    float* bu  = out + (size_t)b * (kNE*3);
    float* bv  = bu  + (size_t)kB * (kNE*3);
    float* kbo = bv  + (size_t)kB * (kNE*3);
    const int o = 6*lane;

    nts2(bu + o    , uA.x, uA.y);
    nts2(bu + o + 2, uA.z, uB.x);
    nts2(bu + o + 4, uB.y, uB.z);

    nts2(bv + o    , vvA.x, vvA.y);
    nts2(bv + o + 2, vvA.z, vvB.x);
    nts2(bv + o + 4, vvB.y, vvB.z);

    nts2(kbo + o    , kb0.x, kb0.y);
    nts2(kbo + o + 2, kb0.z, kb1.x);
    nts2(kbo + o + 4, kb1.y, kb1.z);
}

} // namespace

extern "C" void kernel_launch(void* const* d_in, const int* in_sizes, int n_in,
                              void* d_out, int out_size, void* d_ws, size_t ws_size,
                              hipStream_t stream)
{
    const float* verts = (const float*)d_in[0];
    const float* dinit = (const float*)d_in[1];
    const float* restL = (const float*)d_in[2];
    float* out = (float*)d_out;

    dim3 grid(kB / kRPB);
    dim3 block(64 * kRPB);
    hipLaunchKernelGGL(rod_frames_scan_kernel, grid, block, 0, stream,
                       verts, dinit, restL, out);
}